// Round 1
// baseline (1853.279 us; speedup 1.0000x reference)
//
#include <hip/hip_runtime.h>

// Problem constants (B=16, E=2048, H=16, D=128, S_old=4095, S=4096)
#define SCALE_QK 0.08838834764831845f  // 1/sqrt(128)

// ---------------------------------------------------------------------------
// Kernel 1: setup — last[b] = sum(mask[b,:]) - 1 ; qkv <- attn bias ; out <- proj bias
// grid 48 x 256
// ---------------------------------------------------------------------------
__global__ __launch_bounds__(256) void k_setup(const int* __restrict__ mask,
    const float* __restrict__ attn_b, const float* __restrict__ proj_b,
    int* __restrict__ last, float* __restrict__ qkv, float* __restrict__ out)
{
    int blk = blockIdx.x, t = threadIdx.x;
    if (blk < 16) {
        int s = 0;
        for (int i = t; i < 4096; i += 256) s += mask[blk * 4096 + i];
        #pragma unroll
        for (int m = 32; m >= 1; m >>= 1) s += __shfl_xor(s, m, 64);
        __shared__ int red[4];
        int wave = t >> 6, lane = t & 63;
        if (lane == 0) red[wave] = s;
        __syncthreads();
        if (t == 0) last[blk] = red[0] + red[1] + red[2] + red[3] - 1;
    } else if (blk < 40) {
        int j = (blk - 16) * 256 + t;          // 0..6143
        float bv = attn_b[j];
        #pragma unroll
        for (int b = 0; b < 16; ++b) qkv[b * 6144 + j] = bv;
    } else {
        int j = (blk - 40) * 256 + t;          // 0..2047
        float bv = proj_b[j];
        #pragma unroll
        for (int b = 0; b < 16; ++b) out[b * 2048 + j] = bv;
    }
}

// ---------------------------------------------------------------------------
// Kernel 2: qkv[b,j] += sum_e hidden[b,e]*W[e,j]  (qkv pre-initialized to bias)
// grid (24 j-tiles, 8 e-splits) x 256
// ---------------------------------------------------------------------------
__global__ __launch_bounds__(256) void k_qkv(const float* __restrict__ hidden,
    const float* __restrict__ w, float* __restrict__ qkv)
{
    __shared__ float lds[256 * 20];            // [e][b], pad 20 keeps float4 align
    int t = threadIdx.x;
    int j = blockIdx.x * 256 + t;
    int e0 = blockIdx.y * 256;
    for (int idx = t; idx < 4096; idx += 256) {
        int b = idx >> 8, e = idx & 255;
        lds[e * 20 + b] = hidden[b * 2048 + e0 + e];
    }
    __syncthreads();
    float acc[16];
    #pragma unroll
    for (int b = 0; b < 16; ++b) acc[b] = 0.f;
    const float* wp = w + (long)e0 * 6144 + j;
    for (int e = 0; e < 256; ++e) {
        float wv = wp[(long)e * 6144];
        const float4* lr = (const float4*)(lds + e * 20);
        float4 h0 = lr[0], h1 = lr[1], h2 = lr[2], h3 = lr[3];
        acc[0]  += wv * h0.x; acc[1]  += wv * h0.y; acc[2]  += wv * h0.z; acc[3]  += wv * h0.w;
        acc[4]  += wv * h1.x; acc[5]  += wv * h1.y; acc[6]  += wv * h1.z; acc[7]  += wv * h1.w;
        acc[8]  += wv * h2.x; acc[9]  += wv * h2.y; acc[10] += wv * h2.z; acc[11] += wv * h2.w;
        acc[12] += wv * h3.x; acc[13] += wv * h3.y; acc[14] += wv * h3.z; acc[15] += wv * h3.w;
    }
    #pragma unroll
    for (int b = 0; b < 16; ++b) atomicAdd(qkv + b * 6144 + j, acc[b]);
}

// ---------------------------------------------------------------------------
// Kernel 3: stream K: write keys output AND per-head QK dots -> scores[b][h][s]
// grid (16 b, 256 s-chunks of 16) x 256
// thread t covers elements [4t,4t+4) (head t>>5) and [1024+4t,...) (head 8+(t>>5))
// ---------------------------------------------------------------------------
__global__ __launch_bounds__(256) void k_kstream(const float* __restrict__ kc,
    const float* __restrict__ qkv, const float* __restrict__ bias_row,
    const int* __restrict__ mask, const int* __restrict__ last,
    float* __restrict__ keys, float* __restrict__ scores)
{
    __shared__ float q_lds[2048];
    int b = blockIdx.x, t = threadIdx.x;
    int s0 = blockIdx.y * 16;
    const float4* qsrc = (const float4*)(qkv + b * 6144);
    ((float4*)q_lds)[t]       = qsrc[t];
    ((float4*)q_lds)[t + 256] = qsrc[t + 256];
    __syncthreads();
    int lastb = last[b];
    float4 q0 = *(const float4*)(q_lds + 4 * t);
    float4 q1 = *(const float4*)(q_lds + 1024 + 4 * t);
    for (int s = s0; s < s0 + 16; ++s) {
        float4 k0, k1;
        if (s == lastb) {
            const float4* src = (const float4*)(qkv + b * 6144 + 2048);
            k0 = src[t]; k1 = src[t + 256];
        } else if (s < 4095) {
            const float4* src = (const float4*)(kc + ((long)(b * 4095 + s)) * 2048);
            k0 = src[t]; k1 = src[t + 256];
        } else {
            k0 = make_float4(0.f, 0.f, 0.f, 0.f); k1 = k0;
        }
        float4* dst = (float4*)(keys + ((long)(b * 4096 + s)) * 2048);
        dst[t] = k0; dst[t + 256] = k1;
        float a0 = k0.x * q0.x + k0.y * q0.y + k0.z * q0.z + k0.w * q0.w;
        float a1 = k1.x * q1.x + k1.y * q1.y + k1.z * q1.z + k1.w * q1.w;
        #pragma unroll
        for (int m = 16; m >= 1; m >>= 1) {
            a0 += __shfl_xor(a0, m, 64);
            a1 += __shfl_xor(a1, m, 64);
        }
        if ((t & 31) == 0) {
            int head0 = t >> 5;                 // 0..7
            float bs = bias_row[s];             // attn_bias[0, s]
            bool live = (mask[b * 4096 + s] != 0);
            float sc0 = live ? (a0 * SCALE_QK + bs) : -1e9f;
            float sc1 = live ? (a1 * SCALE_QK + bs) : -1e9f;
            scores[(b * 16 + head0) * 4096 + s]     = sc0;
            scores[(b * 16 + head0 + 8) * 4096 + s] = sc1;
        }
    }
}

// ---------------------------------------------------------------------------
// Kernel 4: in-place softmax over scores rows. grid 256 (b*16+h) x 256
// ---------------------------------------------------------------------------
__global__ __launch_bounds__(256) void k_softmax(float* __restrict__ scores)
{
    float* p = scores + (long)blockIdx.x * 4096;
    int t = threadIdx.x;
    float v[16];
    float m = -3.4e38f;
    #pragma unroll
    for (int i = 0; i < 16; ++i) { v[i] = p[t + 256 * i]; m = fmaxf(m, v[i]); }
    #pragma unroll
    for (int k = 32; k >= 1; k >>= 1) m = fmaxf(m, __shfl_xor(m, k, 64));
    __shared__ float redm[4];
    __shared__ float reds[4];
    int wave = t >> 6, lane = t & 63;
    if (lane == 0) redm[wave] = m;
    __syncthreads();
    m = fmaxf(fmaxf(redm[0], redm[1]), fmaxf(redm[2], redm[3]));
    float sum = 0.f;
    #pragma unroll
    for (int i = 0; i < 16; ++i) { v[i] = __expf(v[i] - m); sum += v[i]; }
    #pragma unroll
    for (int k = 32; k >= 1; k >>= 1) sum += __shfl_xor(sum, k, 64);
    if (lane == 0) reds[wave] = sum;
    __syncthreads();
    sum = reds[0] + reds[1] + reds[2] + reds[3];
    float inv = 1.f / sum;
    #pragma unroll
    for (int i = 0; i < 16; ++i) p[t + 256 * i] = v[i] * inv;
}

// ---------------------------------------------------------------------------
// Kernel 5: stream V: write values output AND accumulate partial ctx per chunk
// grid (16 b, 64 chunks of 64 s) x 256
// ---------------------------------------------------------------------------
__global__ __launch_bounds__(256) void k_vstream(const float* __restrict__ vc,
    const float* __restrict__ qkv, const float* __restrict__ attn,
    const int* __restrict__ last, float* __restrict__ values,
    float* __restrict__ partial)
{
    int b = blockIdx.x, t = threadIdx.x;
    int chunk = blockIdx.y;
    int s0 = chunk * 64;
    int lastb = last[b];
    int h0 = t >> 5;
    const float* a0p = attn + (b * 16 + h0) * 4096;
    const float* a1p = a0p + 8 * 4096;
    float4 acc0 = make_float4(0.f, 0.f, 0.f, 0.f);
    float4 acc1 = make_float4(0.f, 0.f, 0.f, 0.f);
    for (int s = s0; s < s0 + 64; ++s) {
        float4 v0, v1;
        if (s == lastb) {
            const float4* src = (const float4*)(qkv + b * 6144 + 4096);
            v0 = src[t]; v1 = src[t + 256];
        } else if (s < 4095) {
            const float4* src = (const float4*)(vc + ((long)(b * 4095 + s)) * 2048);
            v0 = src[t]; v1 = src[t + 256];
        } else {
            v0 = make_float4(0.f, 0.f, 0.f, 0.f); v1 = v0;
        }
        float4* dst = (float4*)(values + ((long)(b * 4096 + s)) * 2048);
        dst[t] = v0; dst[t + 256] = v1;
        float w0 = a0p[s], w1 = a1p[s];
        acc0.x += w0 * v0.x; acc0.y += w0 * v0.y; acc0.z += w0 * v0.z; acc0.w += w0 * v0.w;
        acc1.x += w1 * v1.x; acc1.y += w1 * v1.y; acc1.z += w1 * v1.z; acc1.w += w1 * v1.w;
    }
    float4* pp = (float4*)(partial + ((long)(b * 64 + chunk)) * 2048);
    pp[t] = acc0; pp[t + 256] = acc1;
}

// ---------------------------------------------------------------------------
// Kernel 6: ctx[b][e] = sum_c partial[b][c][e]. grid (16, 8) x 256
// ---------------------------------------------------------------------------
__global__ __launch_bounds__(256) void k_reduce(const float* __restrict__ partial,
    float* __restrict__ ctx)
{
    int b = blockIdx.x, t = threadIdx.x;
    int e = blockIdx.y * 256 + t;
    const float* p = partial + (long)b * 64 * 2048 + e;
    float acc = 0.f;
    for (int c = 0; c < 64; ++c) acc += p[c * 2048];
    ctx[b * 2048 + e] = acc;
}

// ---------------------------------------------------------------------------
// Kernel 7: out[b,j] += sum_e ctx[b,e]*Wp[e,j]  (out pre-initialized to bias)
// grid (8 j-tiles, 16 e-splits) x 256
// ---------------------------------------------------------------------------
__global__ __launch_bounds__(256) void k_proj(const float* __restrict__ ctx,
    const float* __restrict__ w, float* __restrict__ out)
{
    __shared__ float lds[128 * 20];
    int t = threadIdx.x;
    int j = blockIdx.x * 256 + t;
    int e0 = blockIdx.y * 128;
    for (int idx = t; idx < 2048; idx += 256) {
        int b = idx >> 7, e = idx & 127;
        lds[e * 20 + b] = ctx[b * 2048 + e0 + e];
    }
    __syncthreads();
    float acc[16];
    #pragma unroll
    for (int b = 0; b < 16; ++b) acc[b] = 0.f;
    const float* wp = w + (long)e0 * 2048 + j;
    for (int e = 0; e < 128; ++e) {
        float wv = wp[(long)e * 2048];
        const float4* lr = (const float4*)(lds + e * 20);
        float4 h0 = lr[0], h1 = lr[1], h2 = lr[2], h3 = lr[3];
        acc[0]  += wv * h0.x; acc[1]  += wv * h0.y; acc[2]  += wv * h0.z; acc[3]  += wv * h0.w;
        acc[4]  += wv * h1.x; acc[5]  += wv * h1.y; acc[6]  += wv * h1.z; acc[7]  += wv * h1.w;
        acc[8]  += wv * h2.x; acc[9]  += wv * h2.y; acc[10] += wv * h2.z; acc[11] += wv * h2.w;
        acc[12] += wv * h3.x; acc[13] += wv * h3.y; acc[14] += wv * h3.z; acc[15] += wv * h3.w;
    }
    #pragma unroll
    for (int b = 0; b < 16; ++b) atomicAdd(out + b * 2048 + j, acc[b]);
}

// ---------------------------------------------------------------------------
extern "C" void kernel_launch(void* const* d_in, const int* in_sizes, int n_in,
                              void* d_out, int out_size, void* d_ws, size_t ws_size,
                              hipStream_t stream)
{
    const float* hidden    = (const float*)d_in[0];  // (16,1,2048)
    const float* k_cache   = (const float*)d_in[1];  // (16,4095,2048)
    const float* v_cache   = (const float*)d_in[2];  // (16,4095,2048)
    const int*   mask      = (const int*)  d_in[3];  // (16,4096)
    const float* attn_bias = (const float*)d_in[4];  // (4096,4096) — only row 0 used
    const float* c_attn_w  = (const float*)d_in[5];  // (2048,6144)
    const float* c_attn_b  = (const float*)d_in[6];  // (6144,)
    const float* c_proj_w  = (const float*)d_in[7];  // (2048,2048)
    const float* c_proj_b  = (const float*)d_in[8];  // (2048,)

    float* out    = (float*)d_out;                        // (16,1,2048)
    float* keys   = out + 32768;                          // (16,4096,2048)
    float* values = keys + (size_t)16 * 4096 * 2048;      // (16,4096,2048)

    // workspace layout (floats): last[16 ints] | qkv 98304 | scores 1048576 |
    // partial 2097152 | ctx 32768   (~13.1 MB)
    int*   last    = (int*)d_ws;
    float* wsf     = (float*)d_ws;
    float* qkv     = wsf + 64;
    float* scores  = qkv + 98304;
    float* partial = scores + 1048576;
    float* ctx     = partial + 2097152;

    k_setup  <<<48,            256, 0, stream>>>(mask, c_attn_b, c_proj_b, last, qkv, out);
    k_qkv    <<<dim3(24, 8),   256, 0, stream>>>(hidden, c_attn_w, qkv);
    k_kstream<<<dim3(16, 256), 256, 0, stream>>>(k_cache, qkv, attn_bias, mask, last, keys, scores);
    k_softmax<<<256,           256, 0, stream>>>(scores);
    k_vstream<<<dim3(16, 64),  256, 0, stream>>>(v_cache, qkv, scores, last, values, partial);
    k_reduce <<<dim3(16, 8),   256, 0, stream>>>(partial, ctx);
    k_proj   <<<dim3(8, 16),   256, 0, stream>>>(ctx, c_proj_w, out);
}